// Round 1
// baseline (5092.443 us; speedup 1.0000x reference)
//
#include <hip/hip_runtime.h>

// Attention2: point-cloud attention, N=1M, KNN=9, C_in=C_inner=20, REPEAT=2.
// All data fp32. Three training-mode BNs require global stats passes.

constexpr int KNN_ = 9;
constexpr int CI   = 20;   // in/inner channels
constexpr int CC   = 23;   // CI + 3 (xyz)
constexpr int CAT  = 40;   // CI + CI
constexpr float EPS = 1e-5f;

// ---- block-wide reduce of CNT float partials into f64 global accumulators ----
template <int CNT>
__device__ inline void block_reduce_add(float (&v)[CNT], double* __restrict__ dst,
                                        float* __restrict__ lds /*4*CNT floats*/) {
    const int lane = threadIdx.x & 63;
    const int wid  = threadIdx.x >> 6;
#pragma unroll
    for (int i = 0; i < CNT; ++i) {
        float x = v[i];
#pragma unroll
        for (int off = 32; off > 0; off >>= 1) x += __shfl_down(x, off);
        if (lane == 0) lds[wid * CNT + i] = x;
    }
    __syncthreads();
    if (threadIdx.x < CNT) {
        float x = lds[threadIdx.x] + lds[CNT + threadIdx.x] +
                  lds[2 * CNT + threadIdx.x] + lds[3 * CNT + threadIdx.x];
        atomicAdd(dst + threadIdx.x, (double)x);
    }
}

// ---- K1: per-channel sum/sumsq of conv1 output over all (n,k) — BN1 stats ----
__global__ __launch_bounds__(256) void k1_stats(
    const float* __restrict__ points, const float* __restrict__ feature,
    const int* __restrict__ index, const float* __restrict__ W1,
    double* __restrict__ stats, int N)
{
    __shared__ float Ws[CI * CC];
    __shared__ float red[4 * 2 * CI];
    for (int i = threadIdx.x; i < CI * CC; i += 256) Ws[i] = W1[i];
    __syncthreads();

    float acc[2 * CI];
#pragma unroll
    for (int i = 0; i < 2 * CI; ++i) acc[i] = 0.f;

    const int total = N * KNN_;
    for (int pid = blockIdx.x * 256 + threadIdx.x; pid < total; pid += gridDim.x * 256) {
        const int n = pid / KNN_;
        const int j = index[pid];
        const float4* fj = reinterpret_cast<const float4*>(feature + (size_t)j * CI);
        const float4 f0 = fj[0], f1 = fj[1], f2 = fj[2], f3 = fj[3], f4 = fj[4];
        float in[CC];
        in[0]=f0.x; in[1]=f0.y; in[2]=f0.z; in[3]=f0.w;
        in[4]=f1.x; in[5]=f1.y; in[6]=f1.z; in[7]=f1.w;
        in[8]=f2.x; in[9]=f2.y; in[10]=f2.z; in[11]=f2.w;
        in[12]=f3.x; in[13]=f3.y; in[14]=f3.z; in[15]=f3.w;
        in[16]=f4.x; in[17]=f4.y; in[18]=f4.z; in[19]=f4.w;
        in[20] = points[3*j+0] - points[3*n+0];
        in[21] = points[3*j+1] - points[3*n+1];
        in[22] = points[3*j+2] - points[3*n+2];
#pragma unroll
        for (int o = 0; o < CI; ++o) {
            float y = 0.f;
#pragma unroll
            for (int c = 0; c < CC; ++c) y = fmaf(Ws[o * CC + c], in[c], y);
            acc[o] += y;
            acc[CI + o] = fmaf(y, y, acc[CI + o]);
        }
    }
    __syncthreads();
    block_reduce_add<2 * CI>(acc, stats, red);
}

// ---- K3: recompute conv1, apply BN1, attention weights w, aggregate xagg ----
__global__ __launch_bounds__(256) void k3_attn(
    const float* __restrict__ points, const float* __restrict__ feature,
    const int* __restrict__ index, const float* __restrict__ W1,
    const float* __restrict__ g1, const float* __restrict__ b1,
    const double* __restrict__ stats,
    float* __restrict__ wbuf, float* __restrict__ xagg, int N)
{
    __shared__ float Ws[CI * CC];
    __shared__ float sc[CI], sh[CI];
    for (int i = threadIdx.x; i < CI * CC; i += 256) Ws[i] = W1[i];
    if (threadIdx.x < CI) {
        const double M = (double)N * KNN_;
        const double mean = stats[threadIdx.x] / M;
        const double var  = stats[CI + threadIdx.x] / M - mean * mean;
        const float s = g1[threadIdx.x] * rsqrtf((float)var + EPS);
        sc[threadIdx.x] = s;
        sh[threadIdx.x] = b1[threadIdx.x] - (float)mean * s;
    }
    __syncthreads();

    const int n = blockIdx.x * 256 + threadIdx.x;
    if (n >= N) return;

    const float pnx = points[3*n], pny = points[3*n+1], pnz = points[3*n+2];
    float x0[CI], accv[CI];
#pragma unroll
    for (int o = 0; o < CI; ++o) accv[o] = 0.f;

#pragma unroll
    for (int k = 0; k < KNN_; ++k) {
        const int j = index[n * KNN_ + k];
        const float4* fj = reinterpret_cast<const float4*>(feature + (size_t)j * CI);
        const float4 f0 = fj[0], f1 = fj[1], f2 = fj[2], f3 = fj[3], f4 = fj[4];
        float in[CC];
        in[0]=f0.x; in[1]=f0.y; in[2]=f0.z; in[3]=f0.w;
        in[4]=f1.x; in[5]=f1.y; in[6]=f1.z; in[7]=f1.w;
        in[8]=f2.x; in[9]=f2.y; in[10]=f2.z; in[11]=f2.w;
        in[12]=f3.x; in[13]=f3.y; in[14]=f3.z; in[15]=f3.w;
        in[16]=f4.x; in[17]=f4.y; in[18]=f4.z; in[19]=f4.w;
        in[20] = points[3*j+0] - pnx;
        in[21] = points[3*j+1] - pny;
        in[22] = points[3*j+2] - pnz;
        float xk[CI];
#pragma unroll
        for (int o = 0; o < CI; ++o) {
            float y = 0.f;
#pragma unroll
            for (int c = 0; c < CC; ++c) y = fmaf(Ws[o * CC + c], in[c], y);
            xk[o] = fmaf(y, sc[o], sh[o]);
        }
        if (k == 0) {
#pragma unroll
            for (int o = 0; o < CI; ++o) x0[o] = xk[o];
        }
        float w = 0.f;
#pragma unroll
        for (int o = 0; o < CI; ++o) w = fmaf(xk[o], x0[o], w);
        wbuf[n * KNN_ + k] = w;
#pragma unroll
        for (int o = 0; o < CI; ++o) accv[o] = fmaf(xk[o], w, accv[o]);
    }
    float4* xo = reinterpret_cast<float4*>(xagg + (size_t)n * CI);
    xo[0] = make_float4(accv[0],  accv[1],  accv[2],  accv[3]);
    xo[1] = make_float4(accv[4],  accv[5],  accv[6],  accv[7]);
    xo[2] = make_float4(accv[8],  accv[9],  accv[10], accv[11]);
    xo[3] = make_float4(accv[12], accv[13], accv[14], accv[15]);
    xo[4] = make_float4(accv[16], accv[17], accv[18], accv[19]);
}

// ---- K4: x2[n] = sum_k xagg[idx[n,k]]*w[n,k]; fused BN2 stats ----
__global__ __launch_bounds__(256) void k4_prop(
    const int* __restrict__ index, const float* __restrict__ wbuf,
    const float* __restrict__ xagg, float* __restrict__ x2,
    double* __restrict__ stats2, int N)
{
    __shared__ float red[4 * 2 * CI];
    float st[2 * CI];
#pragma unroll
    for (int i = 0; i < 2 * CI; ++i) st[i] = 0.f;

    for (int n = blockIdx.x * 256 + threadIdx.x; n < N; n += gridDim.x * 256) {
        float accv[CI];
#pragma unroll
        for (int o = 0; o < CI; ++o) accv[o] = 0.f;
#pragma unroll
        for (int k = 0; k < KNN_; ++k) {
            const int j = index[n * KNN_ + k];
            const float w = wbuf[n * KNN_ + k];
            const float4* g = reinterpret_cast<const float4*>(xagg + (size_t)j * CI);
            const float4 g0 = g[0], g1_ = g[1], g2_ = g[2], g3_ = g[3], g4 = g[4];
            float gv[CI];
            gv[0]=g0.x; gv[1]=g0.y; gv[2]=g0.z; gv[3]=g0.w;
            gv[4]=g1_.x; gv[5]=g1_.y; gv[6]=g1_.z; gv[7]=g1_.w;
            gv[8]=g2_.x; gv[9]=g2_.y; gv[10]=g2_.z; gv[11]=g2_.w;
            gv[12]=g3_.x; gv[13]=g3_.y; gv[14]=g3_.z; gv[15]=g3_.w;
            gv[16]=g4.x; gv[17]=g4.y; gv[18]=g4.z; gv[19]=g4.w;
#pragma unroll
            for (int o = 0; o < CI; ++o) accv[o] = fmaf(gv[o], w, accv[o]);
        }
        float4* xo = reinterpret_cast<float4*>(x2 + (size_t)n * CI);
        xo[0] = make_float4(accv[0],  accv[1],  accv[2],  accv[3]);
        xo[1] = make_float4(accv[4],  accv[5],  accv[6],  accv[7]);
        xo[2] = make_float4(accv[8],  accv[9],  accv[10], accv[11]);
        xo[3] = make_float4(accv[12], accv[13], accv[14], accv[15]);
        xo[4] = make_float4(accv[16], accv[17], accv[18], accv[19]);
#pragma unroll
        for (int o = 0; o < CI; ++o) {
            st[o] += accv[o];
            st[CI + o] = fmaf(accv[o], accv[o], st[CI + o]);
        }
    }
    __syncthreads();
    block_reduce_add<2 * CI>(st, stats2, red);
}

// ---- K6: h=relu(bn2(x2)); cat=[h,feature]; y=Wr1@cat+br1; fused BN3 stats ----
__global__ __launch_bounds__(256) void k6_refine1(
    const float* __restrict__ x2, const float* __restrict__ feature,
    const float* __restrict__ g2, const float* __restrict__ b2,
    const float* __restrict__ Wr1, const float* __restrict__ br1,
    const double* __restrict__ stats2,
    float* __restrict__ ybuf, double* __restrict__ stats3, int N)
{
    __shared__ float Ws[CI * CAT];
    __shared__ float sc[CI], sh[CI];
    __shared__ float red[4 * 2 * CI];
    for (int i = threadIdx.x; i < CI * CAT; i += 256) Ws[i] = Wr1[i];
    if (threadIdx.x < CI) {
        const double M = (double)N;
        const double mean = stats2[threadIdx.x] / M;
        const double var  = stats2[CI + threadIdx.x] / M - mean * mean;
        const float s = g2[threadIdx.x] * rsqrtf((float)var + EPS);
        sc[threadIdx.x] = s;
        sh[threadIdx.x] = b2[threadIdx.x] - (float)mean * s;
    }
    __syncthreads();

    float st[2 * CI];
#pragma unroll
    for (int i = 0; i < 2 * CI; ++i) st[i] = 0.f;

    for (int n = blockIdx.x * 256 + threadIdx.x; n < N; n += gridDim.x * 256) {
        float cat[CAT];
        const float4* xi = reinterpret_cast<const float4*>(x2 + (size_t)n * CI);
#pragma unroll
        for (int q = 0; q < 5; ++q) {
            const float4 v = xi[q];
            cat[4*q+0] = fmaxf(fmaf(v.x, sc[4*q+0], sh[4*q+0]), 0.f);
            cat[4*q+1] = fmaxf(fmaf(v.y, sc[4*q+1], sh[4*q+1]), 0.f);
            cat[4*q+2] = fmaxf(fmaf(v.z, sc[4*q+2], sh[4*q+2]), 0.f);
            cat[4*q+3] = fmaxf(fmaf(v.w, sc[4*q+3], sh[4*q+3]), 0.f);
        }
        const float4* fi = reinterpret_cast<const float4*>(feature + (size_t)n * CI);
#pragma unroll
        for (int q = 0; q < 5; ++q) {
            const float4 v = fi[q];
            cat[CI+4*q+0] = v.x; cat[CI+4*q+1] = v.y;
            cat[CI+4*q+2] = v.z; cat[CI+4*q+3] = v.w;
        }
        float yv[CI];
#pragma unroll
        for (int o = 0; o < CI; ++o) {
            float y = br1[o];
#pragma unroll
            for (int c = 0; c < CAT; ++c) y = fmaf(Ws[o * CAT + c], cat[c], y);
            yv[o] = y;
            st[o] += y;
            st[CI + o] = fmaf(y, y, st[CI + o]);
        }
        float4* yo = reinterpret_cast<float4*>(ybuf + (size_t)n * CI);
        yo[0] = make_float4(yv[0],  yv[1],  yv[2],  yv[3]);
        yo[1] = make_float4(yv[4],  yv[5],  yv[6],  yv[7]);
        yo[2] = make_float4(yv[8],  yv[9],  yv[10], yv[11]);
        yo[3] = make_float4(yv[12], yv[13], yv[14], yv[15]);
        yo[4] = make_float4(yv[16], yv[17], yv[18], yv[19]);
    }
    __syncthreads();
    block_reduce_add<2 * CI>(st, stats3, red);
}

// ---- K8: out = relu(bn3(y)) @ Wr2.T + br2 ----
__global__ __launch_bounds__(256) void k8_out(
    const float* __restrict__ ybuf,
    const float* __restrict__ g3, const float* __restrict__ b3,
    const float* __restrict__ Wr2, const float* __restrict__ br2,
    const double* __restrict__ stats3, float* __restrict__ out, int N)
{
    __shared__ float Ws[CI * CI];
    __shared__ float sc[CI], sh[CI];
    for (int i = threadIdx.x; i < CI * CI; i += 256) Ws[i] = Wr2[i];
    if (threadIdx.x < CI) {
        const double M = (double)N;
        const double mean = stats3[threadIdx.x] / M;
        const double var  = stats3[CI + threadIdx.x] / M - mean * mean;
        const float s = g3[threadIdx.x] * rsqrtf((float)var + EPS);
        sc[threadIdx.x] = s;
        sh[threadIdx.x] = b3[threadIdx.x] - (float)mean * s;
    }
    __syncthreads();

    const int n = blockIdx.x * 256 + threadIdx.x;
    if (n >= N) return;

    float z[CI];
    const float4* yi = reinterpret_cast<const float4*>(ybuf + (size_t)n * CI);
#pragma unroll
    for (int q = 0; q < 5; ++q) {
        const float4 v = yi[q];
        z[4*q+0] = fmaxf(fmaf(v.x, sc[4*q+0], sh[4*q+0]), 0.f);
        z[4*q+1] = fmaxf(fmaf(v.y, sc[4*q+1], sh[4*q+1]), 0.f);
        z[4*q+2] = fmaxf(fmaf(v.z, sc[4*q+2], sh[4*q+2]), 0.f);
        z[4*q+3] = fmaxf(fmaf(v.w, sc[4*q+3], sh[4*q+3]), 0.f);
    }
    float ov[CI];
#pragma unroll
    for (int o = 0; o < CI; ++o) {
        float y = br2[o];
#pragma unroll
        for (int c = 0; c < CI; ++c) y = fmaf(Ws[o * CI + c], z[c], y);
        ov[o] = y;
    }
    float4* oo = reinterpret_cast<float4*>(out + (size_t)n * CI);
    oo[0] = make_float4(ov[0],  ov[1],  ov[2],  ov[3]);
    oo[1] = make_float4(ov[4],  ov[5],  ov[6],  ov[7]);
    oo[2] = make_float4(ov[8],  ov[9],  ov[10], ov[11]);
    oo[3] = make_float4(ov[12], ov[13], ov[14], ov[15]);
    oo[4] = make_float4(ov[16], ov[17], ov[18], ov[19]);
}

extern "C" void kernel_launch(void* const* d_in, const int* in_sizes, int n_in,
                              void* d_out, int out_size, void* d_ws, size_t ws_size,
                              hipStream_t stream) {
    const float* points  = (const float*)d_in[0];
    const float* feature = (const float*)d_in[1];
    const int*   index   = (const int*)  d_in[2];
    const float* W1      = (const float*)d_in[3];
    const float* g1      = (const float*)d_in[4];
    const float* b1      = (const float*)d_in[5];
    const float* g2      = (const float*)d_in[6];
    const float* b2      = (const float*)d_in[7];
    const float* Wr1     = (const float*)d_in[8];
    const float* br1     = (const float*)d_in[9];
    const float* g3      = (const float*)d_in[10];
    const float* b3      = (const float*)d_in[11];
    const float* Wr2     = (const float*)d_in[12];
    const float* br2     = (const float*)d_in[13];
    const int N = in_sizes[0] / 3;
    float* out = (float*)d_out;

    // workspace layout: [stats: 120 doubles, padded to 1KB][w: N*9 f32][xagg: N*20 f32][x2: N*20 f32]
    // ybuf aliases xagg (dead after k4). Total ~196 MB.
    double* stats = (double*)d_ws;
    char* base = (char*)d_ws;
    float* wbuf = (float*)(base + 1024);
    float* xagg = (float*)(base + 1024 + (size_t)N * KNN_ * sizeof(float));
    float* x2   = (float*)(base + 1024 + (size_t)N * KNN_ * sizeof(float) + (size_t)N * CI * sizeof(float));
    float* ybuf = xagg;

    hipMemsetAsync(stats, 0, 6 * CI * sizeof(double), stream);

    const int B = 256;
    const int gridN = (N + B - 1) / B;
    k1_stats  <<<2048, B, 0, stream>>>(points, feature, index, W1, stats, N);
    k3_attn   <<<gridN, B, 0, stream>>>(points, feature, index, W1, g1, b1, stats, wbuf, xagg, N);
    k4_prop   <<<2048, B, 0, stream>>>(index, wbuf, xagg, x2, stats + 2 * CI, N);
    k6_refine1<<<2048, B, 0, stream>>>(x2, feature, g2, b2, Wr1, br1, stats + 2 * CI, ybuf, stats + 4 * CI, N);
    k8_out    <<<gridN, B, 0, stream>>>(ybuf, g3, b3, Wr2, br2, stats + 4 * CI, out, N);
}